// Round 1
// baseline (1005.983 us; speedup 1.0000x reference)
//
#include <hip/hip_runtime.h>
#include <stdint.h>

#define A 15
#define H_ 34
#define W_ 34
#define HW (H_*W_)
#define N (A*HW)            // 17340
#define MAX_CAND 3000
#define TOP_N 300
#define NWORDS 47           // ceil(3000/64)
#define JCH 2176            // 8 chunks * 2176 = 17408 >= N

__constant__ float c_aw[A] = {9.232984f, 16.0f, 27.712813f, 18.465969f, 32.0f, 55.425626f,
                              36.931937f, 64.0f, 110.851252f, 73.863875f, 128.0f, 221.702503f,
                              147.72775f, 256.0f, 443.405007f};
__constant__ float c_ah[A] = {27.72668f, 16.0f, 9.237604f, 55.453359f, 32.0f, 18.475209f,
                              110.906719f, 64.0f, 36.950417f, 221.813438f, 128.0f, 73.900834f,
                              443.626876f, 256.0f, 147.801669f};

// ---------------------------------------------------------------------------
// K1: decode boxes, scores, masked score, 64-bit stable sort key; zero rank.
// Exact reference op order; __fmul_rn/__fadd_rn block FMA contraction.
// ---------------------------------------------------------------------------
__global__ __launch_bounds__(256) void k_boxes(
    const float* __restrict__ cls, const float* __restrict__ pred,
    const int* __restrict__ iminfo,
    float4* __restrict__ boxes, float2* __restrict__ scores,
    float* __restrict__ maskv, unsigned long long* __restrict__ keys,
    int* __restrict__ rank)
{
    int m = blockIdx.x * 256 + threadIdx.x;
    if (m >= N) return;
    rank[m] = 0;

    int a  = m % A;
    int hw = m / A;
    int w  = hw % W_;
    int h  = hw / W_;

    float ow = (float)iminfo[1];
    float oh = (float)iminfo[0];

    float aw = c_aw[a], ah = c_ah[a];
    float xm = __fmul_rn(-0.5f, __fsub_rn(aw, 1.0f));
    float ym = __fmul_rn(-0.5f, __fsub_rn(ah, 1.0f));
    // shifts for row m: [w*8, h*8, w*8, h*8]  (ij-meshgrid quirk cancels)
    float sxw = (float)(w * 8);
    float syh = (float)(h * 8);
    float x1 = __fadd_rn(sxw, xm);
    float y1 = __fadd_rn(syh, ym);
    float x2 = __fadd_rn(sxw, -xm);
    float y2 = __fadd_rn(syh, -ym);

    float widths  = __fadd_rn(__fsub_rn(x2, x1), 1.0f);
    float heights = __fadd_rn(__fsub_rn(y2, y1), 1.0f);
    float ctr_x = __fadd_rn(x1, __fmul_rn(0.5f, __fsub_rn(widths, 1.0f)));
    float ctr_y = __fadd_rn(y1, __fmul_rn(0.5f, __fsub_rn(heights, 1.0f)));

    const float std0 = 0.12677f,   std1 = 0.095741f, std2 = 0.3173f,    std3 = 0.281042f;
    const float mu0  = 0.000437f,  mu1  = 0.002586f, mu2  = -0.123953f, mu3  = -0.081469f;
    int pb = a * 4 * HW + hw;
    float d0 = __fadd_rn(__fmul_rn(pred[pb + 0 * HW], std0), mu0);
    float d1 = __fadd_rn(__fmul_rn(pred[pb + 1 * HW], std1), mu1);
    float d2 = __fadd_rn(__fmul_rn(pred[pb + 2 * HW], std2), mu2);
    float d3 = __fadd_rn(__fmul_rn(pred[pb + 3 * HW], std3), mu3);

    float pcx = __fadd_rn(__fmul_rn(d0, widths),  ctr_x);
    float pcy = __fadd_rn(__fmul_rn(d1, heights), ctr_y);
    float pw  = __fmul_rn(expf(d2), widths);
    float ph  = __fmul_rn(expf(d3), heights);

    float hpw = __fmul_rn(0.5f, __fsub_rn(pw, 1.0f));
    float hph = __fmul_rn(0.5f, __fsub_rn(ph, 1.0f));
    float bx1 = __fsub_rn(pcx, hpw);
    float by1 = __fsub_rn(pcy, hph);
    float bx2 = __fadd_rn(pcx, hpw);
    float by2 = __fadd_rn(pcy, hph);

    float ow1 = __fsub_rn(ow, 1.0f), oh1 = __fsub_rn(oh, 1.0f);
    bx1 = fminf(fmaxf(bx1, 0.0f), ow1);
    by1 = fminf(fmaxf(by1, 0.0f), oh1);
    bx2 = fminf(fmaxf(bx2, 0.0f), ow1);
    by2 = fminf(fmaxf(by2, 0.0f), oh1);

    float s0 = cls[a * HW + hw];
    float s1 = cls[(A + a) * HW + hw];

    float wsv = __fadd_rn(__fsub_rn(bx2, bx1), 1.0f);
    float hsv = __fadd_rn(__fsub_rn(by2, by1), 1.0f);
    bool keep = (s1 > 0.2f) && ((wsv >= 6.16056f) || (hsv >= 6.16056f));
    float masked = keep ? s1 : -1e30f;

    boxes[m]  = make_float4(bx1, by1, bx2, by2);
    scores[m] = make_float2(s0, s1);
    maskv[m]  = masked;

    // order-preserving key: score descending, index ascending (lax.top_k stable)
    unsigned int fb = __float_as_uint(masked);
    fb = (fb & 0x80000000u) ? ~fb : (fb | 0x80000000u);
    keys[m] = ((unsigned long long)fb << 32) | (unsigned int)(~(unsigned int)m);
}

// ---------------------------------------------------------------------------
// K2a: rank[i] = #{j : key_j > key_i}.  2D grid: x = element blocks,
// y = 8 j-chunks staged through LDS; partial counts accumulated atomically.
// ---------------------------------------------------------------------------
__global__ __launch_bounds__(256) void k_rank(
    const unsigned long long* __restrict__ keys, int* __restrict__ rank)
{
    __shared__ unsigned long long tile[JCH];
    int j0 = blockIdx.y * JCH;
    for (int t = threadIdx.x; t < JCH; t += 256) {
        int g = j0 + t;
        tile[t] = (g < N) ? keys[g] : 0ull;   // 0 < every real key
    }
    __syncthreads();

    int i = blockIdx.x * 256 + threadIdx.x;
    if (i >= N) return;
    unsigned long long mk = keys[i];
    int cnt = 0;
    #pragma unroll 4
    for (int t = 0; t < JCH; ++t) cnt += (tile[t] > mk) ? 1 : 0;
    if (cnt) atomicAdd(&rank[i], cnt);
}

// ---------------------------------------------------------------------------
// K2b: scatter rank<3000 into candidate slots (permutation => every slot hit).
// ---------------------------------------------------------------------------
__global__ __launch_bounds__(256) void k_scatter(
    const int* __restrict__ rank, const float4* __restrict__ boxes,
    const float2* __restrict__ scores, const float* __restrict__ maskv,
    float4* __restrict__ cboxes, float2* __restrict__ cscores,
    int* __restrict__ cvalid)
{
    int i = blockIdx.x * 256 + threadIdx.x;
    if (i >= N) return;
    int r = rank[i];
    if (r < MAX_CAND) {
        cboxes[r]  = boxes[i];
        cscores[r] = scores[i];
        cvalid[r]  = (maskv[i] > (-1e30f * 0.5f)) ? 1 : 0;
    }
}

// ---------------------------------------------------------------------------
// K3: suppression bitmask. block i, 256 threads sweep j; ballot -> 64b words.
// bit set iff iou(i,j) > 0.7 && j > i.
// ---------------------------------------------------------------------------
__global__ __launch_bounds__(256) void k_iou(
    const float4* __restrict__ cboxes, unsigned long long* __restrict__ sup)
{
    int i = blockIdx.x;
    float4 bi = cboxes[i];
    float area_i = __fmul_rn(__fsub_rn(bi.z, bi.x), __fsub_rn(bi.w, bi.y));
    int lane = threadIdx.x & 63;
    int wave = threadIdx.x >> 6;

    for (int jb = 0; jb < (MAX_CAND + 255) / 256; ++jb) {
        int j = jb * 256 + threadIdx.x;
        bool p = false;
        if (j < MAX_CAND && j > i) {
            float4 bj = cboxes[j];
            float iw = fmaxf(__fsub_rn(fminf(bi.z, bj.z), fmaxf(bi.x, bj.x)), 0.0f);
            float ih = fmaxf(__fsub_rn(fminf(bi.w, bj.w), fmaxf(bi.y, bj.y)), 0.0f);
            float inter  = __fmul_rn(iw, ih);
            float area_j = __fmul_rn(__fsub_rn(bj.z, bj.x), __fsub_rn(bj.w, bj.y));
            float denom  = fmaxf(__fsub_rn(__fadd_rn(area_i, area_j), inter), 1e-12f);
            p = (inter / denom) > 0.7f;
        }
        unsigned long long msk = __ballot(p);
        int word = jb * 4 + wave;
        if (lane == 0 && word < NWORDS) sup[(size_t)i * NWORDS + word] = msk;
    }
}

// ---------------------------------------------------------------------------
// K4+K5: single-wave sequential greedy NMS over register-resident bitmask
// (47 words across lanes, __shfl broadcast of alive bit, 8-deep row prefetch),
// then prefix-popcount selection + output write.
// ---------------------------------------------------------------------------
__global__ __launch_bounds__(64) void k_nms_out(
    const unsigned long long* __restrict__ sup, const int* __restrict__ cvalid,
    const float4* __restrict__ cboxes, const float2* __restrict__ cscores,
    float* __restrict__ out)
{
    int lane = threadIdx.x;

    // zero full output (harness poisons d_out with 0xAA every call)
    for (int t = lane; t < TOP_N * 5 + TOP_N * 2; t += 64) out[t] = 0.0f;

    // pack initial keep mask
    unsigned long long kp = 0ull;
    if (lane < NWORDS) {
        for (int b = 0; b < 64; ++b) {
            int j = lane * 64 + b;
            if (j < MAX_CAND && cvalid[j]) kp |= (1ull << b);
        }
    }

    // sequential scan, 8-deep prefetch of suppression rows
    for (int i0 = 0; i0 < MAX_CAND; i0 += 8) {
        unsigned long long r[8];
        #pragma unroll
        for (int u = 0; u < 8; ++u)
            r[u] = (lane < NWORDS) ? sup[(size_t)(i0 + u) * NWORDS + lane] : 0ull;
        #pragma unroll
        for (int u = 0; u < 8; ++u) {
            int i = i0 + u;
            unsigned long long kw = __shfl(kp, i >> 6, 64);
            if ((kw >> (i & 63)) & 1ull) kp &= ~r[u];
        }
    }

    __syncthreads();  // order zero-fill writes before scatter writes

    __shared__ int cnts[64];
    cnts[lane] = __popcll(kp);
    __syncthreads();
    int prefix = 0;
    for (int t = 0; t < lane; ++t) prefix += cnts[t];

    unsigned long long mrem = kp;
    while (mrem) {
        int b = __ffsll(mrem) - 1;
        mrem &= mrem - 1;
        if (prefix < TOP_N) {
            int j = lane * 64 + b;
            float4 bx = cboxes[j];
            float2 sc = cscores[j];
            out[prefix * 5 + 0] = 0.0f;
            out[prefix * 5 + 1] = bx.x;
            out[prefix * 5 + 2] = bx.y;
            out[prefix * 5 + 3] = bx.z;
            out[prefix * 5 + 4] = bx.w;
            out[TOP_N * 5 + prefix * 2 + 0] = sc.x;
            out[TOP_N * 5 + prefix * 2 + 1] = sc.y;
        }
        prefix++;
    }
}

// ---------------------------------------------------------------------------
extern "C" void kernel_launch(void* const* d_in, const int* in_sizes, int n_in,
                              void* d_out, int out_size, void* d_ws, size_t ws_size,
                              hipStream_t stream) {
    const float* cls    = (const float*)d_in[0];
    const float* pred   = (const float*)d_in[1];
    const int*   iminfo = (const int*)d_in[2];
    float* out = (float*)d_out;

    char* p = (char*)d_ws;
    auto alloc = [&](size_t bytes) -> char* {
        char* q = p;
        p += (bytes + 255) & ~(size_t)255;
        return q;
    };
    float4* boxes  = (float4*)alloc((size_t)N * sizeof(float4));
    float2* scores = (float2*)alloc((size_t)N * sizeof(float2));
    float*  maskv  = (float*) alloc((size_t)N * sizeof(float));
    unsigned long long* keys = (unsigned long long*)alloc((size_t)N * 8);
    int*    rank   = (int*)   alloc((size_t)N * 4);
    float4* cboxes  = (float4*)alloc((size_t)MAX_CAND * sizeof(float4));
    float2* cscores = (float2*)alloc((size_t)MAX_CAND * sizeof(float2));
    int*    cvalid  = (int*)   alloc((size_t)MAX_CAND * 4);
    unsigned long long* sup = (unsigned long long*)alloc((size_t)MAX_CAND * NWORDS * 8);

    int nb = (N + 255) / 256;  // 68
    k_boxes <<<nb, 256, 0, stream>>>(cls, pred, iminfo, boxes, scores, maskv, keys, rank);
    k_rank  <<<dim3(nb, 8), 256, 0, stream>>>(keys, rank);
    k_scatter<<<nb, 256, 0, stream>>>(rank, boxes, scores, maskv, cboxes, cscores, cvalid);
    k_iou   <<<MAX_CAND, 256, 0, stream>>>(cboxes, sup);
    k_nms_out<<<1, 64, 0, stream>>>(sup, cvalid, cboxes, cscores, out);
}

// Round 2
// 393.898 us; speedup vs baseline: 2.5539x; 2.5539x over previous
//
#include <hip/hip_runtime.h>
#include <stdint.h>

#define A 15
#define H_ 34
#define W_ 34
#define HW (H_*W_)
#define N (A*HW)            // 17340
#define MAX_CAND 3000
#define TOP_N 300
#define NWORDS 47           // ceil(3000/64)
#define CHUNK_W 3008        // 64 rows * 47 words per chunk
#define JCH 2176            // 8 chunks * 2176 = 17408 >= N

__constant__ float c_aw[A] = {9.232984f, 16.0f, 27.712813f, 18.465969f, 32.0f, 55.425626f,
                              36.931937f, 64.0f, 110.851252f, 73.863875f, 128.0f, 221.702503f,
                              147.72775f, 256.0f, 443.405007f};
__constant__ float c_ah[A] = {27.72668f, 16.0f, 9.237604f, 55.453359f, 32.0f, 18.475209f,
                              110.906719f, 64.0f, 36.950417f, 221.813438f, 128.0f, 73.900834f,
                              443.626876f, 256.0f, 147.801669f};

// ---------------------------------------------------------------------------
// K1: decode boxes, scores, masked score, 64-bit stable sort key; zero rank
// and packed keep-mask. Exact reference op order; __f*_rn blocks contraction.
// ---------------------------------------------------------------------------
__global__ __launch_bounds__(256) void k_boxes(
    const float* __restrict__ cls, const float* __restrict__ pred,
    const int* __restrict__ iminfo,
    float4* __restrict__ boxes, float2* __restrict__ scores,
    unsigned long long* __restrict__ keys,
    int* __restrict__ rank, unsigned long long* __restrict__ kpm)
{
    int m = blockIdx.x * 256 + threadIdx.x;
    if (m >= N) return;
    rank[m] = 0;
    if (m < NWORDS) kpm[m] = 0ull;

    int a  = m % A;
    int hw = m / A;
    int w  = hw % W_;
    int h  = hw / W_;

    float ow = (float)iminfo[1];
    float oh = (float)iminfo[0];

    float aw = c_aw[a], ah = c_ah[a];
    float xm = __fmul_rn(-0.5f, __fsub_rn(aw, 1.0f));
    float ym = __fmul_rn(-0.5f, __fsub_rn(ah, 1.0f));
    float sxw = (float)(w * 8);
    float syh = (float)(h * 8);
    float x1 = __fadd_rn(sxw, xm);
    float y1 = __fadd_rn(syh, ym);
    float x2 = __fadd_rn(sxw, -xm);
    float y2 = __fadd_rn(syh, -ym);

    float widths  = __fadd_rn(__fsub_rn(x2, x1), 1.0f);
    float heights = __fadd_rn(__fsub_rn(y2, y1), 1.0f);
    float ctr_x = __fadd_rn(x1, __fmul_rn(0.5f, __fsub_rn(widths, 1.0f)));
    float ctr_y = __fadd_rn(y1, __fmul_rn(0.5f, __fsub_rn(heights, 1.0f)));

    const float std0 = 0.12677f,   std1 = 0.095741f, std2 = 0.3173f,    std3 = 0.281042f;
    const float mu0  = 0.000437f,  mu1  = 0.002586f, mu2  = -0.123953f, mu3  = -0.081469f;
    int pb = a * 4 * HW + hw;
    float d0 = __fadd_rn(__fmul_rn(pred[pb + 0 * HW], std0), mu0);
    float d1 = __fadd_rn(__fmul_rn(pred[pb + 1 * HW], std1), mu1);
    float d2 = __fadd_rn(__fmul_rn(pred[pb + 2 * HW], std2), mu2);
    float d3 = __fadd_rn(__fmul_rn(pred[pb + 3 * HW], std3), mu3);

    float pcx = __fadd_rn(__fmul_rn(d0, widths),  ctr_x);
    float pcy = __fadd_rn(__fmul_rn(d1, heights), ctr_y);
    float pw  = __fmul_rn(expf(d2), widths);
    float ph  = __fmul_rn(expf(d3), heights);

    float hpw = __fmul_rn(0.5f, __fsub_rn(pw, 1.0f));
    float hph = __fmul_rn(0.5f, __fsub_rn(ph, 1.0f));
    float bx1 = __fsub_rn(pcx, hpw);
    float by1 = __fsub_rn(pcy, hph);
    float bx2 = __fadd_rn(pcx, hpw);
    float by2 = __fadd_rn(pcy, hph);

    float ow1 = __fsub_rn(ow, 1.0f), oh1 = __fsub_rn(oh, 1.0f);
    bx1 = fminf(fmaxf(bx1, 0.0f), ow1);
    by1 = fminf(fmaxf(by1, 0.0f), oh1);
    bx2 = fminf(fmaxf(bx2, 0.0f), ow1);
    by2 = fminf(fmaxf(by2, 0.0f), oh1);

    float s0 = cls[a * HW + hw];
    float s1 = cls[(A + a) * HW + hw];

    float wsv = __fadd_rn(__fsub_rn(bx2, bx1), 1.0f);
    float hsv = __fadd_rn(__fsub_rn(by2, by1), 1.0f);
    bool keep = (s1 > 0.2f) && ((wsv >= 6.16056f) || (hsv >= 6.16056f));
    float masked = keep ? s1 : -1e30f;

    boxes[m]  = make_float4(bx1, by1, bx2, by2);
    scores[m] = make_float2(s0, s1);

    unsigned int fb = __float_as_uint(masked);
    fb = (fb & 0x80000000u) ? ~fb : (fb | 0x80000000u);
    keys[m] = ((unsigned long long)fb << 32) | (unsigned int)(~(unsigned int)m);
}

// ---------------------------------------------------------------------------
// K2a: rank[i] = #{j : key_j > key_i}.
// ---------------------------------------------------------------------------
__global__ __launch_bounds__(256) void k_rank(
    const unsigned long long* __restrict__ keys, int* __restrict__ rank)
{
    __shared__ unsigned long long tile[JCH];
    int j0 = blockIdx.y * JCH;
    for (int t = threadIdx.x; t < JCH; t += 256) {
        int g = j0 + t;
        tile[t] = (g < N) ? keys[g] : 0ull;
    }
    __syncthreads();

    int i = blockIdx.x * 256 + threadIdx.x;
    if (i >= N) return;
    unsigned long long mk = keys[i];
    int cnt = 0;
    #pragma unroll 4
    for (int t = 0; t < JCH; ++t) cnt += (tile[t] > mk) ? 1 : 0;
    if (cnt) atomicAdd(&rank[i], cnt);
}

// ---------------------------------------------------------------------------
// K2b: scatter rank<3000 into candidate slots; valid bit -> packed kpm.
// ---------------------------------------------------------------------------
__global__ __launch_bounds__(256) void k_scatter(
    const int* __restrict__ rank, const float4* __restrict__ boxes,
    const float2* __restrict__ scores, const unsigned long long* __restrict__ keys,
    float4* __restrict__ cboxes, float2* __restrict__ cscores,
    unsigned long long* __restrict__ kpm)
{
    int i = blockIdx.x * 256 + threadIdx.x;
    if (i >= N) return;
    int r = rank[i];
    if (r < MAX_CAND) {
        cboxes[r]  = boxes[i];
        cscores[r] = scores[i];
        // valid iff masked score > -5e29  <=>  key's score field not -1e30
        unsigned int fb = (unsigned int)(keys[i] >> 32);
        float masked = (fb & 0x80000000u) ? __uint_as_float(fb & 0x7fffffffu)
                                          : __uint_as_float(~fb);
        if (masked > (-1e30f * 0.5f))
            atomicOr(&kpm[r >> 6], 1ull << (r & 63));
    }
}

// ---------------------------------------------------------------------------
// K3: suppression bitmask. bit j of row i set iff iou(i,j)>0.7 && j>i.
// ---------------------------------------------------------------------------
__global__ __launch_bounds__(256) void k_iou(
    const float4* __restrict__ cboxes, unsigned long long* __restrict__ sup)
{
    int i = blockIdx.x;
    float4 bi = cboxes[i];
    float area_i = __fmul_rn(__fsub_rn(bi.z, bi.x), __fsub_rn(bi.w, bi.y));
    int lane = threadIdx.x & 63;
    int wave = threadIdx.x >> 6;

    for (int jb = 0; jb < (MAX_CAND + 255) / 256; ++jb) {
        int j = jb * 256 + threadIdx.x;
        bool p = false;
        if (j < MAX_CAND && j > i) {
            float4 bj = cboxes[j];
            float iw = fmaxf(__fsub_rn(fminf(bi.z, bj.z), fmaxf(bi.x, bj.x)), 0.0f);
            float ih = fmaxf(__fsub_rn(fminf(bi.w, bj.w), fmaxf(bi.y, bj.y)), 0.0f);
            float inter  = __fmul_rn(iw, ih);
            float area_j = __fmul_rn(__fsub_rn(bj.z, bj.x), __fsub_rn(bj.w, bj.y));
            float denom  = fmaxf(__fsub_rn(__fadd_rn(area_i, area_j), inter), 1e-12f);
            p = (inter / denom) > 0.7f;
        }
        unsigned long long msk = __ballot(p);
        int word = jb * 4 + wave;
        if (lane == 0 && word < NWORDS) sup[(size_t)i * NWORDS + word] = msk;
    }
}

// ---------------------------------------------------------------------------
// K4: chunked greedy NMS. 47 chunks of 64 rows; double-buffered LDS staging
// (loads issued before wave0's serial resolve = T14 async split); ffs-skip
// serial resolve (iterations = kept count, not 64); OR-fold into later words.
// Then prefix-scan selection + output write.
// ---------------------------------------------------------------------------
__global__ __launch_bounds__(1024) void k_nms_out(
    const unsigned long long* __restrict__ sup,
    const unsigned long long* __restrict__ kpm,
    const float4* __restrict__ cboxes, const float2* __restrict__ cscores,
    float* __restrict__ out)
{
    __shared__ unsigned long long buf[2][CHUNK_W];
    __shared__ unsigned long long kp[NWORDS + 1];

    int tid  = threadIdx.x;
    int lane = tid & 63;
    int wave = tid >> 6;

    // zero full output (harness poisons d_out with 0xAA every call)
    for (int t = tid; t < TOP_N * 7; t += 1024) out[t] = 0.0f;

    if (tid < NWORDS) kp[tid] = kpm[tid];

    // stage chunk 0
    {
        unsigned long long v0 = sup[tid];
        unsigned long long v1 = sup[tid + 1024];
        unsigned long long v2 = (tid + 2048 < CHUNK_W) ? sup[tid + 2048] : 0ull;
        buf[0][tid] = v0;
        buf[0][tid + 1024] = v1;
        if (tid + 2048 < CHUNK_W) buf[0][tid + 2048] = v2;
    }
    __syncthreads();

    for (int w = 0; w < NWORDS; ++w) {
        int cur = w & 1;
        bool havnext = (w + 1 < NWORDS);

        // issue next chunk's global loads EARLY (latency hides under resolve)
        unsigned long long v0 = 0, v1 = 0, v2 = 0;
        if (havnext) {
            const unsigned long long* src = sup + (size_t)(w + 1) * CHUNK_W;
            v0 = src[tid];
            v1 = src[tid + 1024];
            v2 = (tid + 2048 < CHUNK_W) ? src[tid + 2048] : 0ull;
        }

        if (wave == 0) {
            // lane l holds row (64w+l)'s word w
            unsigned long long intra = buf[cur][lane * NWORDS + w];
            unsigned long long kw  = kp[w];
            unsigned long long rem = kw;
            while (rem) {
                int b = __ffsll((long long)rem) - 1;       // lowest survivor = kept
                unsigned long long row = __shfl(intra, b, 64);
                kw  &= ~row;                                // row has only bits > b
                rem &= ~row;
                rem &= ~(1ull << b);
            }
            if (lane == 0) kp[w] = kw;
            // fold kept rows' suppression into later words (independent LDS reads)
            if (lane < NWORDS && lane > w) {
                unsigned long long comb = 0, t2 = kw;
                while (t2) {
                    int b = __ffsll((long long)t2) - 1;
                    t2 &= t2 - 1;
                    comb |= buf[cur][b * NWORDS + lane];
                }
                kp[lane] &= ~comb;
            }
        }

        // complete the staged copy (vmcnt wait lands here, after resolve)
        if (havnext) {
            int nxt = cur ^ 1;
            buf[nxt][tid] = v0;
            buf[nxt][tid + 1024] = v1;
            if (tid + 2048 < CHUNK_W) buf[nxt][tid + 2048] = v2;
        }
        __syncthreads();
    }

    // selection + output (wave 0 only)
    if (wave == 0) {
        unsigned long long kw = (lane < NWORDS) ? kp[lane] : 0ull;
        int cnt = __popcll(kw);
        int pre = cnt;
        for (int d = 1; d < 64; d <<= 1) {
            int o = __shfl_up(pre, d, 64);
            if (lane >= d) pre += o;
        }
        int prefix = pre - cnt;  // exclusive prefix of kept counts
        while (kw) {
            int b = __ffsll((long long)kw) - 1;
            kw &= kw - 1;
            if (prefix < TOP_N) {
                int j = lane * 64 + b;
                float4 bx = cboxes[j];
                float2 sc = cscores[j];
                out[prefix * 5 + 0] = 0.0f;
                out[prefix * 5 + 1] = bx.x;
                out[prefix * 5 + 2] = bx.y;
                out[prefix * 5 + 3] = bx.z;
                out[prefix * 5 + 4] = bx.w;
                out[TOP_N * 5 + prefix * 2 + 0] = sc.x;
                out[TOP_N * 5 + prefix * 2 + 1] = sc.y;
            }
            prefix++;
        }
    }
}

// ---------------------------------------------------------------------------
extern "C" void kernel_launch(void* const* d_in, const int* in_sizes, int n_in,
                              void* d_out, int out_size, void* d_ws, size_t ws_size,
                              hipStream_t stream) {
    const float* cls    = (const float*)d_in[0];
    const float* pred   = (const float*)d_in[1];
    const int*   iminfo = (const int*)d_in[2];
    float* out = (float*)d_out;

    char* p = (char*)d_ws;
    auto alloc = [&](size_t bytes) -> char* {
        char* q = p;
        p += (bytes + 255) & ~(size_t)255;
        return q;
    };
    float4* boxes  = (float4*)alloc((size_t)N * sizeof(float4));
    float2* scores = (float2*)alloc((size_t)N * sizeof(float2));
    unsigned long long* keys = (unsigned long long*)alloc((size_t)N * 8);
    int*    rank   = (int*)   alloc((size_t)N * 4);
    float4* cboxes  = (float4*)alloc((size_t)MAX_CAND * sizeof(float4));
    float2* cscores = (float2*)alloc((size_t)MAX_CAND * sizeof(float2));
    unsigned long long* kpm = (unsigned long long*)alloc((size_t)NWORDS * 8);
    unsigned long long* sup = (unsigned long long*)alloc((size_t)MAX_CAND * NWORDS * 8);

    int nb = (N + 255) / 256;  // 68
    k_boxes <<<nb, 256, 0, stream>>>(cls, pred, iminfo, boxes, scores, keys, rank, kpm);
    k_rank  <<<dim3(nb, 8), 256, 0, stream>>>(keys, rank);
    k_scatter<<<nb, 256, 0, stream>>>(rank, boxes, scores, keys, cboxes, cscores, kpm);
    k_iou   <<<MAX_CAND, 256, 0, stream>>>(cboxes, sup);
    k_nms_out<<<1, 1024, 0, stream>>>(sup, kpm, cboxes, cscores, out);
}

// Round 3
// 142.797 us; speedup vs baseline: 7.0448x; 2.7584x over previous
//
#include <hip/hip_runtime.h>
#include <stdint.h>

#define A 15
#define H_ 34
#define W_ 34
#define HW (H_*W_)
#define N (A*HW)            // 17340
#define MAX_CAND 3000
#define TOP_N 300
#define NWORDS 47           // ceil(3000/64)
#define CHUNK_W 3008        // 64 rows * 47 words per chunk
#define JCH 2176            // 8 chunks * 2176 = 17408 >= N

__constant__ float c_aw[A] = {9.232984f, 16.0f, 27.712813f, 18.465969f, 32.0f, 55.425626f,
                              36.931937f, 64.0f, 110.851252f, 73.863875f, 128.0f, 221.702503f,
                              147.72775f, 256.0f, 443.405007f};
__constant__ float c_ah[A] = {27.72668f, 16.0f, 9.237604f, 55.453359f, 32.0f, 18.475209f,
                              110.906719f, 64.0f, 36.950417f, 221.813438f, 128.0f, 73.900834f,
                              443.626876f, 256.0f, 147.801669f};

// ---------------------------------------------------------------------------
// K1: decode boxes, scores, 64-bit stable sort key; zero rank + packed keep.
// Exact reference op order; __f*_rn blocks FMA contraction.
// ---------------------------------------------------------------------------
__global__ __launch_bounds__(256) void k_boxes(
    const float* __restrict__ cls, const float* __restrict__ pred,
    const int* __restrict__ iminfo,
    float4* __restrict__ boxes, float2* __restrict__ scores,
    unsigned long long* __restrict__ keys,
    int* __restrict__ rank, unsigned long long* __restrict__ kpm)
{
    int m = blockIdx.x * 256 + threadIdx.x;
    if (m >= N) return;
    rank[m] = 0;
    if (m < NWORDS) kpm[m] = 0ull;

    int a  = m % A;
    int hw = m / A;
    int w  = hw % W_;
    int h  = hw / W_;

    float ow = (float)iminfo[1];
    float oh = (float)iminfo[0];

    float aw = c_aw[a], ah = c_ah[a];
    float xm = __fmul_rn(-0.5f, __fsub_rn(aw, 1.0f));
    float ym = __fmul_rn(-0.5f, __fsub_rn(ah, 1.0f));
    float sxw = (float)(w * 8);
    float syh = (float)(h * 8);
    float x1 = __fadd_rn(sxw, xm);
    float y1 = __fadd_rn(syh, ym);
    float x2 = __fadd_rn(sxw, -xm);
    float y2 = __fadd_rn(syh, -ym);

    float widths  = __fadd_rn(__fsub_rn(x2, x1), 1.0f);
    float heights = __fadd_rn(__fsub_rn(y2, y1), 1.0f);
    float ctr_x = __fadd_rn(x1, __fmul_rn(0.5f, __fsub_rn(widths, 1.0f)));
    float ctr_y = __fadd_rn(y1, __fmul_rn(0.5f, __fsub_rn(heights, 1.0f)));

    const float std0 = 0.12677f,   std1 = 0.095741f, std2 = 0.3173f,    std3 = 0.281042f;
    const float mu0  = 0.000437f,  mu1  = 0.002586f, mu2  = -0.123953f, mu3  = -0.081469f;
    int pb = a * 4 * HW + hw;
    float d0 = __fadd_rn(__fmul_rn(pred[pb + 0 * HW], std0), mu0);
    float d1 = __fadd_rn(__fmul_rn(pred[pb + 1 * HW], std1), mu1);
    float d2 = __fadd_rn(__fmul_rn(pred[pb + 2 * HW], std2), mu2);
    float d3 = __fadd_rn(__fmul_rn(pred[pb + 3 * HW], std3), mu3);

    float pcx = __fadd_rn(__fmul_rn(d0, widths),  ctr_x);
    float pcy = __fadd_rn(__fmul_rn(d1, heights), ctr_y);
    float pw  = __fmul_rn(expf(d2), widths);
    float ph  = __fmul_rn(expf(d3), heights);

    float hpw = __fmul_rn(0.5f, __fsub_rn(pw, 1.0f));
    float hph = __fmul_rn(0.5f, __fsub_rn(ph, 1.0f));
    float bx1 = __fsub_rn(pcx, hpw);
    float by1 = __fsub_rn(pcy, hph);
    float bx2 = __fadd_rn(pcx, hpw);
    float by2 = __fadd_rn(pcy, hph);

    float ow1 = __fsub_rn(ow, 1.0f), oh1 = __fsub_rn(oh, 1.0f);
    bx1 = fminf(fmaxf(bx1, 0.0f), ow1);
    by1 = fminf(fmaxf(by1, 0.0f), oh1);
    bx2 = fminf(fmaxf(bx2, 0.0f), ow1);
    by2 = fminf(fmaxf(by2, 0.0f), oh1);

    float s0 = cls[a * HW + hw];
    float s1 = cls[(A + a) * HW + hw];

    float wsv = __fadd_rn(__fsub_rn(bx2, bx1), 1.0f);
    float hsv = __fadd_rn(__fsub_rn(by2, by1), 1.0f);
    bool keep = (s1 > 0.2f) && ((wsv >= 6.16056f) || (hsv >= 6.16056f));
    float masked = keep ? s1 : -1e30f;

    boxes[m]  = make_float4(bx1, by1, bx2, by2);
    scores[m] = make_float2(s0, s1);

    unsigned int fb = __float_as_uint(masked);
    fb = (fb & 0x80000000u) ? ~fb : (fb | 0x80000000u);
    keys[m] = ((unsigned long long)fb << 32) | (unsigned int)(~(unsigned int)m);
}

// ---------------------------------------------------------------------------
// K2a: rank[i] = #{j : key_j > key_i}.
// ---------------------------------------------------------------------------
__global__ __launch_bounds__(256) void k_rank(
    const unsigned long long* __restrict__ keys, int* __restrict__ rank)
{
    __shared__ unsigned long long tile[JCH];
    int j0 = blockIdx.y * JCH;
    for (int t = threadIdx.x; t < JCH; t += 256) {
        int g = j0 + t;
        tile[t] = (g < N) ? keys[g] : 0ull;
    }
    __syncthreads();

    int i = blockIdx.x * 256 + threadIdx.x;
    if (i >= N) return;
    unsigned long long mk = keys[i];
    int cnt = 0;
    #pragma unroll 4
    for (int t = 0; t < JCH; ++t) cnt += (tile[t] > mk) ? 1 : 0;
    if (cnt) atomicAdd(&rank[i], cnt);
}

// ---------------------------------------------------------------------------
// K2b: scatter rank<3000 into candidate slots; valid bit -> packed kpm.
// ---------------------------------------------------------------------------
__global__ __launch_bounds__(256) void k_scatter(
    const int* __restrict__ rank, const float4* __restrict__ boxes,
    const float2* __restrict__ scores, const unsigned long long* __restrict__ keys,
    float4* __restrict__ cboxes, float2* __restrict__ cscores,
    unsigned long long* __restrict__ kpm)
{
    int i = blockIdx.x * 256 + threadIdx.x;
    if (i >= N) return;
    int r = rank[i];
    if (r < MAX_CAND) {
        cboxes[r]  = boxes[i];
        cscores[r] = scores[i];
        unsigned int fb = (unsigned int)(keys[i] >> 32);
        float masked = (fb & 0x80000000u) ? __uint_as_float(fb & 0x7fffffffu)
                                          : __uint_as_float(~fb);
        if (masked > (-1e30f * 0.5f))
            atomicOr(&kpm[r >> 6], 1ull << (r & 63));
    }
}

// ---------------------------------------------------------------------------
// K3: suppression bitmask. bit j of row i set iff iou(i,j)>0.7 && j>i.
// ---------------------------------------------------------------------------
__global__ __launch_bounds__(256) void k_iou(
    const float4* __restrict__ cboxes, unsigned long long* __restrict__ sup)
{
    int i = blockIdx.x;
    float4 bi = cboxes[i];
    float area_i = __fmul_rn(__fsub_rn(bi.z, bi.x), __fsub_rn(bi.w, bi.y));
    int lane = threadIdx.x & 63;
    int wave = threadIdx.x >> 6;

    for (int jb = 0; jb < (MAX_CAND + 255) / 256; ++jb) {
        int j = jb * 256 + threadIdx.x;
        bool p = false;
        if (j < MAX_CAND && j > i) {
            float4 bj = cboxes[j];
            float iw = fmaxf(__fsub_rn(fminf(bi.z, bj.z), fmaxf(bi.x, bj.x)), 0.0f);
            float ih = fmaxf(__fsub_rn(fminf(bi.w, bj.w), fmaxf(bi.y, bj.y)), 0.0f);
            float inter  = __fmul_rn(iw, ih);
            float area_j = __fmul_rn(__fsub_rn(bj.z, bj.x), __fsub_rn(bj.w, bj.y));
            float denom  = fmaxf(__fsub_rn(__fadd_rn(area_i, area_j), inter), 1e-12f);
            p = (inter / denom) > 0.7f;
        }
        unsigned long long msk = __ballot(p);
        int word = jb * 4 + wave;
        if (lane == 0 && word < NWORDS) sup[(size_t)i * NWORDS + word] = msk;
    }
}

// ---------------------------------------------------------------------------
// K4: chunked greedy NMS with (a) EARLY EXIT once kept>=300 (reference only
// consumes first 300 kept), (b) nonzero-row skip in the serial resolve,
// (c) fixed-trip predicated fold (pipelined LDS reads), (d) parallel output.
// ---------------------------------------------------------------------------
__global__ __launch_bounds__(1024) void k_nms_out(
    const unsigned long long* __restrict__ sup,
    const unsigned long long* __restrict__ kpm,
    const float4* __restrict__ cboxes, const float2* __restrict__ cscores,
    float* __restrict__ out)
{
    __shared__ unsigned long long buf[2][CHUNK_W];
    __shared__ unsigned long long kp[NWORDS + 1];
    __shared__ int sel[TOP_N];
    __shared__ int s_stop;

    int tid  = threadIdx.x;
    int lane = tid & 63;
    int wave = tid >> 6;

    // zero full output (harness poisons d_out with 0xAA every call)
    for (int t = tid; t < TOP_N * 7; t += 1024) out[t] = 0.0f;
    for (int t = tid; t < TOP_N; t += 1024) sel[t] = -1;

    if (tid < NWORDS) kp[tid] = kpm[tid];

    // stage chunk 0
    {
        unsigned long long v0 = sup[tid];
        unsigned long long v1 = sup[tid + 1024];
        unsigned long long v2 = (tid + 2048 < CHUNK_W) ? sup[tid + 2048] : 0ull;
        buf[0][tid] = v0;
        buf[0][tid + 1024] = v1;
        if (tid + 2048 < CHUNK_W) buf[0][tid + 2048] = v2;
    }
    __syncthreads();

    int kept_total = 0;  // uniform within wave0
    for (int w = 0; w < NWORDS; ++w) {
        int cur = w & 1;
        bool havnext = (w + 1 < NWORDS);

        // issue next chunk's global loads EARLY (hide under resolve)
        unsigned long long v0 = 0, v1 = 0, v2 = 0;
        if (havnext) {
            const unsigned long long* src = sup + (size_t)(w + 1) * CHUNK_W;
            v0 = src[tid];
            v1 = src[tid + 1024];
            v2 = (tid + 2048 < CHUNK_W) ? src[tid + 2048] : 0ull;
        }

        if (wave == 0) {
            // lane l holds row (64w+l)'s word w
            unsigned long long intra = buf[cur][lane * NWORDS + w];
            unsigned long long nz = __ballot(intra != 0ull);  // rows that matter
            unsigned long long kw = kp[w];
            unsigned long long rem = kw & nz;   // only visit suppressing survivors
            while (rem) {
                int b = __ffsll((long long)rem) - 1;
                rem &= rem - 1;
                if ((kw >> b) & 1ull) {         // still kept?
                    unsigned long long row = __shfl(intra, b, 64);
                    kw  &= ~row;                // row has only bits > b
                    rem &= ~row;
                }
            }
            if (lane == 0) kp[w] = kw;
            kept_total += __popcll(kw);
            bool stop = (kept_total >= TOP_N) || !havnext;
            if (lane == 0) s_stop = stop ? 1 : 0;

            // fold kept rows into later words: fixed-trip predicated sweep
            if (!stop && lane < NWORDS && lane > w) {
                unsigned long long comb = 0;
                #pragma unroll 8
                for (int b = 0; b < 64; ++b) {
                    unsigned long long r = buf[cur][b * NWORDS + lane];
                    if ((kw >> b) & 1ull) comb |= r;
                }
                kp[lane] &= ~comb;
            }
        }

        // complete the staged copy
        if (havnext) {
            int nxt = cur ^ 1;
            buf[nxt][tid] = v0;
            buf[nxt][tid + 1024] = v1;
            if (tid + 2048 < CHUNK_W) buf[nxt][tid + 2048] = v2;
        }
        __syncthreads();
        if (s_stop) break;   // uniform across block
    }

    // wave0: compact kept indices into sel[] (prefix over words)
    if (wave == 0) {
        unsigned long long kw = (lane < NWORDS) ? kp[lane] : 0ull;
        int cnt = __popcll(kw);
        int pre = cnt;
        for (int d = 1; d < 64; d <<= 1) {
            int o = __shfl_up(pre, d, 64);
            if (lane >= d) pre += o;
        }
        int prefix = pre - cnt;  // exclusive prefix
        while (kw && prefix < TOP_N) {
            int b = __ffsll((long long)kw) - 1;
            kw &= kw - 1;
            sel[prefix] = lane * 64 + b;
            prefix++;
        }
    }
    __syncthreads();

    // parallel gather + write of the 300 outputs
    if (tid < TOP_N) {
        int j = sel[tid];
        if (j >= 0) {
            float4 bx = cboxes[j];
            float2 sc = cscores[j];
            out[tid * 5 + 0] = 0.0f;
            out[tid * 5 + 1] = bx.x;
            out[tid * 5 + 2] = bx.y;
            out[tid * 5 + 3] = bx.z;
            out[tid * 5 + 4] = bx.w;
            out[TOP_N * 5 + tid * 2 + 0] = sc.x;
            out[TOP_N * 5 + tid * 2 + 1] = sc.y;
        }
    }
}

// ---------------------------------------------------------------------------
extern "C" void kernel_launch(void* const* d_in, const int* in_sizes, int n_in,
                              void* d_out, int out_size, void* d_ws, size_t ws_size,
                              hipStream_t stream) {
    const float* cls    = (const float*)d_in[0];
    const float* pred   = (const float*)d_in[1];
    const int*   iminfo = (const int*)d_in[2];
    float* out = (float*)d_out;

    char* p = (char*)d_ws;
    auto alloc = [&](size_t bytes) -> char* {
        char* q = p;
        p += (bytes + 255) & ~(size_t)255;
        return q;
    };
    float4* boxes  = (float4*)alloc((size_t)N * sizeof(float4));
    float2* scores = (float2*)alloc((size_t)N * sizeof(float2));
    unsigned long long* keys = (unsigned long long*)alloc((size_t)N * 8);
    int*    rank   = (int*)   alloc((size_t)N * 4);
    float4* cboxes  = (float4*)alloc((size_t)MAX_CAND * sizeof(float4));
    float2* cscores = (float2*)alloc((size_t)MAX_CAND * sizeof(float2));
    unsigned long long* kpm = (unsigned long long*)alloc((size_t)NWORDS * 8);
    unsigned long long* sup = (unsigned long long*)alloc((size_t)MAX_CAND * NWORDS * 8);

    int nb = (N + 255) / 256;  // 68
    k_boxes <<<nb, 256, 0, stream>>>(cls, pred, iminfo, boxes, scores, keys, rank, kpm);
    k_rank  <<<dim3(nb, 8), 256, 0, stream>>>(keys, rank);
    k_scatter<<<nb, 256, 0, stream>>>(rank, boxes, scores, keys, cboxes, cscores, kpm);
    k_iou   <<<MAX_CAND, 256, 0, stream>>>(cboxes, sup);
    k_nms_out<<<1, 1024, 0, stream>>>(sup, kpm, cboxes, cscores, out);
}